// Round 1
// 283.604 us; speedup vs baseline: 1.1054x; 1.1054x over previous
//
#include <hip/hip_runtime.h>

#define D_FEAT 256
#define UNITS  128

#define NBITS  7            // coarse bin = 128 dst nodes
#define BINSZ  128
#define BINCAP 2432         // Poisson(2048) + 8.5 sigma — cannot overflow for random dst
#define MAXNB  800          // >= ceil(100000/128) = 782

typedef __attribute__((ext_vector_type(8))) short short8;   // 8 bf16 (4 VGPRs)
typedef __attribute__((ext_vector_type(4))) float floatx4;

__device__ inline ushort f2bf(float f) {          // fp32 -> bf16, round-nearest-even
    uint u = __float_as_uint(f);
    uint r = u + 0x7FFF + ((u >> 16) & 1);
    return (ushort)(r >> 16);
}

// ---------------------------------------------------------------------------
// One-time prep: wT_bf16[n][k] = bf16(w[k][n]); 128 x 256, 64 KB, L2-resident.
// ---------------------------------------------------------------------------
__global__ __launch_bounds__(256) void wt_prep_kernel(const float* __restrict__ w,
                                                      ushort* __restrict__ wT) {
    int idx = blockIdx.x * 256 + threadIdx.x;     // 32768 threads
    int n = idx >> 8;
    int k = idx & 255;
    wT[n * 256 + k] = f2bf(w[(size_t)k * UNITS + n]);
}

// ---------------------------------------------------------------------------
// h_bf16[M][128] = bf16( x[M][256] @ w[256][128] ) via mfma_f32_16x16x32_bf16.
//
// v3 (this round): the round-0 counters showed VGPR_Count=52 — the compiler
// had re-serialized the 16 x-loads into tiny load/convert batches and kept
// ~2 of 64 global B-loads in flight => ~375 cy avg stall per memory op,
// 947 GB/s, MfmaUtil 3%.  Fixes:
//   (a) sched_barrier(0) fences pin ALL 16 HBM x-loads in flight per thread
//       (forces ~64 VGPRs of load results to coexist; budget 256 via
//       launch_bounds(256,2); LDS caps us at 2 blocks/CU anyway).
//   (b) wT staged once per block into 64 KB LDS (XOR-swizzled 16B slots so
//       the 16-rows-per-ds_read_b128 B-fragment pattern is bank-balanced);
//       B-reads become ~8-cy ds_read_b128 instead of 64 serial global loads
//       per wave through a thrashed 32 KB L1.
//   Issue order matters: wT chunk loads (L2, ~200cy) FIRST, x loads (HBM,
//   ~900cy) second — vmcnt is in-order, so the ds_writes wait only on the
//   wT chunks and never drain the x-loads.
// ---------------------------------------------------------------------------
__global__ __launch_bounds__(256, 2) void gemm_mfma3_kernel(const float* __restrict__ x,
                                                            const ushort* __restrict__ wT,
                                                            ushort* __restrict__ hb, int M) {
    __shared__ ushort lds_w[128 * 256];   // 64 KB: row n = out-col, 32 x 16B slots, slot^=(n&7)

    const int tid  = threadIdx.x;
    const int wave = tid >> 6;
    const int lane = tid & 63;
    const int quad = lane >> 4;
    const int m16  = lane & 15;

    const int row  = blockIdx.x * 64 + wave * 16 + m16;
    const int rowc = row < M ? row : M - 1;
    const float* xr = x + (size_t)rowc * D_FEAT;

    // ---- phase 0: issue the 16 wT 16B-chunk loads (L2-hot) ----
    short8 wv[16];
    #pragma unroll
    for (int r = 0; r < 16; ++r)
        wv[r] = *(const short8*)(wT + (size_t)(r * 256 + tid) * 8);
    __builtin_amdgcn_sched_barrier(0);

    // ---- phase 1: issue ALL 16 x loads (256 B/lane in flight, HBM) ----
    float4 xv[16];
    #pragma unroll
    for (int s = 0; s < 8; ++s) {
        const float4* p = (const float4*)(xr + s * 32 + quad * 8);
        xv[2 * s]     = p[0];
        xv[2 * s + 1] = p[1];
    }
    __builtin_amdgcn_sched_barrier(0);

    // ---- phase 2: LDS-write wT, XOR-swizzled (waits only the wv loads) ----
    #pragma unroll
    for (int r = 0; r < 16; ++r) {
        int ci = r * 256 + tid;          // 16B chunk index: row = ci>>5, slot = ci&31
        int n  = ci >> 5;
        int ts = (ci & 31) ^ (n & 7);    // swizzled slot
        *(short8*)(lds_w + n * 256 + ts * 8) = wv[r];
    }
    __builtin_amdgcn_sched_barrier(0);

    // ---- phase 3: convert x to bf16 A-fragments (waits the x loads) ----
    short8 afrag[8];
    #pragma unroll
    for (int s = 0; s < 8; ++s) {
        float4 lo = xv[2 * s];
        float4 hi = xv[2 * s + 1];
        union { short8 v; ushort u[8]; } af;
        af.u[0] = f2bf(lo.x); af.u[1] = f2bf(lo.y);
        af.u[2] = f2bf(lo.z); af.u[3] = f2bf(lo.w);
        af.u[4] = f2bf(hi.x); af.u[5] = f2bf(hi.y);
        af.u[6] = f2bf(hi.z); af.u[7] = f2bf(hi.w);
        afrag[s] = af.v;
    }

    __syncthreads();

    // ---- phase 4: MFMA main loop; B-frags via swizzled ds_read_b128 ----
    floatx4 acc[8] = {};
    #pragma unroll
    for (int s = 0; s < 8; ++s) {
        #pragma unroll
        for (int c = 0; c < 8; ++c) {
            int rowb = c * 16 + m16;
            int ts   = (s * 4 + quad) ^ (m16 & 7);
            short8 bfrag = *(const short8*)(lds_w + rowb * 256 + ts * 8);
            acc[c] = __builtin_amdgcn_mfma_f32_16x16x32_bf16(afrag[s], bfrag, acc[c], 0, 0, 0);
        }
    }

    // ---- epilogue: D[row=quad*4+i][col=c*16+m16] -> bf16 ----
    #pragma unroll
    for (int c = 0; c < 8; ++c) {
        #pragma unroll
        for (int i = 0; i < 4; ++i) {
            int r = blockIdx.x * 64 + wave * 16 + quad * 4 + i;
            if (r < M) hb[(size_t)r * UNITS + c * 16 + m16] = f2bf(acc[c][i]);
        }
    }
}

// ---------------------------------------------------------------------------
// Coarse scatter: 256 chunks x 1024 threads. Bins of 128 dst nodes -> ~8
// entries (64 B) per (block,bin) run -> near-line-dense staged writes.
// staged entry: {meta = src | (dst&127)<<20, bits(val)}
// ---------------------------------------------------------------------------
__global__ __launch_bounds__(1024) void coarse_scatter_kernel(const int* __restrict__ src,
                                                              const int* __restrict__ dst,
                                                              const float* __restrict__ vals,
                                                              int* __restrict__ cursor,   // stride 4 ints/bin
                                                              int2* __restrict__ staged,
                                                              int E, int NB, int chunk) {
    __shared__ int s_hist[MAXNB];
    __shared__ int s_base[MAXNB];

    const int tid = threadIdx.x;
    const int T   = 1024;
    const int e0 = blockIdx.x * chunk;
    const int e1 = min(E, e0 + chunk);

    for (int i = tid; i < NB; i += T) s_hist[i] = 0;
    __syncthreads();

    for (int e = e0 + tid; e < e1; e += T)
        atomicAdd(&s_hist[dst[e] >> NBITS], 1);
    __syncthreads();

    for (int b = tid; b < NB; b += T) {
        int c = s_hist[b];
        s_base[b] = (c > 0) ? atomicAdd(&cursor[b * 4], c) : 0;
    }
    __syncthreads();
    for (int i = tid; i < NB; i += T) s_hist[i] = 0;   // reuse as rank counter
    __syncthreads();

    for (int e = e0 + tid; e < e1; e += T) {
        int d = dst[e];
        int b = d >> NBITS;
        int r = s_base[b] + atomicAdd(&s_hist[b], 1);
        if (r < BINCAP) {
            int meta = src[e] | ((d & (BINSZ - 1)) << 20);
            staged[(size_t)b * BINCAP + r] = make_int2(meta, __float_as_int(vals[e]));
        }
    }
}

// ---------------------------------------------------------------------------
// Gather: one block per 128-dst bin. Two-pass counting sort from L2-hot
// staged into sorted LDS, two-level prefix scan, then half-wave per dst with
// 2x-unrolled dual-accumulator inner loop. No global atomics.
// ---------------------------------------------------------------------------
__global__ __launch_bounds__(256) void gather_sort_kernel(const int* __restrict__ cursor,
                                                          const int2* __restrict__ staged,
                                                          const ushort* __restrict__ hb,
                                                          float* __restrict__ out, int N) {
    __shared__ int2 sbuf[BINCAP];
    __shared__ int cnt[BINSZ], ofs[BINSZ], cur[BINSZ];
    __shared__ int gofs[16];

    const int b   = blockIdx.x;
    const int tid = threadIdx.x;

    int n = cursor[b * 4];
    if (n > BINCAP) n = BINCAP;

    for (int i = tid; i < BINSZ; i += 256) cnt[i] = 0;
    __syncthreads();

    const int2* sg = staged + (size_t)b * BINCAP;

    // pass 1: histogram (coalesced global reads)
    for (int i = tid; i < n; i += 256)
        atomicAdd(&cnt[(sg[i].x >> 20) & (BINSZ - 1)], 1);
    __syncthreads();

    // two-level exclusive prefix scan over cnt[128]
    if (tid < 16) {
        int s = 0;
        #pragma unroll
        for (int j = 0; j < 8; ++j) s += cnt[tid * 8 + j];
        gofs[tid] = s;                       // group sums (temporarily)
    }
    __syncthreads();
    if (tid == 0) {
        int run = 0;
        #pragma unroll
        for (int g = 0; g < 16; ++g) { int c = gofs[g]; gofs[g] = run; run += c; }
    }
    __syncthreads();
    if (tid < 16) {
        int run = gofs[tid];
        #pragma unroll
        for (int j = 0; j < 8; ++j) {
            int d = tid * 8 + j;
            int c = cnt[d];
            ofs[d] = run; cur[d] = run; run += c;
        }
    }
    __syncthreads();

    // pass 2: place sorted (re-read is L2-hot)
    for (int i = tid; i < n; i += 256) {
        int2 e = sg[i];
        int pos = atomicAdd(&cur[(e.x >> 20) & (BINSZ - 1)], 1);
        sbuf[pos] = e;
    }
    __syncthreads();

    const int half = tid >> 5;   // 8 half-waves
    const int lane = tid & 31;

    for (int d0 = 0; d0 < BINSZ; d0 += 8) {
        int d  = d0 + half;
        int dg = b * BINSZ + d;
        if (dg >= N) continue;
        int start = ofs[d];
        int c     = cnt[d];

        float a0 = 0.f, a1 = 0.f, a2 = 0.f, a3 = 0.f;
        float b0 = 0.f, b1 = 0.f, b2 = 0.f, b3 = 0.f;
        int j = 0;
        for (; j + 2 <= c; j += 2) {
            int2 ea = sbuf[start + j];
            int2 eb = sbuf[start + j + 1];
            uint2 ha = *(const uint2*)(hb + (size_t)(ea.x & 0xFFFFF) * UNITS + lane * 4);
            uint2 hc = *(const uint2*)(hb + (size_t)(eb.x & 0xFFFFF) * UNITS + lane * 4);
            float va = __int_as_float(ea.y);
            float vb = __int_as_float(eb.y);
            a0 += va * __uint_as_float(ha.x << 16);
            a1 += va * __uint_as_float(ha.x & 0xFFFF0000u);
            a2 += va * __uint_as_float(ha.y << 16);
            a3 += va * __uint_as_float(ha.y & 0xFFFF0000u);
            b0 += vb * __uint_as_float(hc.x << 16);
            b1 += vb * __uint_as_float(hc.x & 0xFFFF0000u);
            b2 += vb * __uint_as_float(hc.y << 16);
            b3 += vb * __uint_as_float(hc.y & 0xFFFF0000u);
        }
        if (j < c) {
            int2 ea = sbuf[start + j];
            uint2 ha = *(const uint2*)(hb + (size_t)(ea.x & 0xFFFFF) * UNITS + lane * 4);
            float va = __int_as_float(ea.y);
            a0 += va * __uint_as_float(ha.x << 16);
            a1 += va * __uint_as_float(ha.x & 0xFFFF0000u);
            a2 += va * __uint_as_float(ha.y << 16);
            a3 += va * __uint_as_float(ha.y & 0xFFFF0000u);
        }
        float4 r = make_float4(a0 + b0, a1 + b1, a2 + b2, a3 + b3);
        *(float4*)(out + (size_t)dg * UNITS + lane * 4) = r;
    }
}

extern "C" void kernel_launch(void* const* d_in, const int* in_sizes, int n_in,
                              void* d_out, int out_size, void* d_ws, size_t ws_size,
                              hipStream_t stream) {
    const float* x        = (const float*)d_in[0];
    const float* w        = (const float*)d_in[1];
    const int*   adj_src  = (const int*)d_in[2];
    const int*   adj_dst  = (const int*)d_in[3];
    const float* adj_vals = (const float*)d_in[4];
    float*       out      = (float*)d_out;

    const int M = in_sizes[0] / D_FEAT;   // 100000 nodes
    const int E = in_sizes[2];            // 1600000 edges
    const int NB = (M + BINSZ - 1) >> NBITS;   // 782 coarse bins

    // Workspace:
    //   hb:     M*128*2           = 25.6 MB
    //   wT:     128*256*2         = 64 KB
    //   cursor: NB*4 ints         = 12.5 KB
    //   staged: NB*BINCAP*8       = 15.2 MB
    char*   ws  = (char*)d_ws;
    ushort* hb  = (ushort*)ws;
    size_t  off = (size_t)M * UNITS * sizeof(ushort);
    off = (off + 255) & ~(size_t)255;
    ushort* wT  = (ushort*)(ws + off);
    off += (size_t)128 * 256 * sizeof(ushort);
    int*    cursor = (int*)(ws + off);
    off += (size_t)NB * 4 * sizeof(int);
    off = (off + 15) & ~(size_t)15;
    int2*   staged = (int2*)(ws + off);

    hipMemsetAsync(cursor, 0, (size_t)NB * 4 * sizeof(int), stream);

    wt_prep_kernel<<<128, 256, 0, stream>>>(w, wT);

    gemm_mfma3_kernel<<<(M + 63) / 64, 256, 0, stream>>>(x, wT, hb, M);

    const int NSCAT = 256;
    const int chunk = (E + NSCAT - 1) / NSCAT;
    coarse_scatter_kernel<<<NSCAT, 1024, 0, stream>>>(adj_src, adj_dst, adj_vals,
                                                      cursor, staged, E, NB, chunk);

    gather_sort_kernel<<<NB, 256, 0, stream>>>(cursor, staged, hb, out, M);
}